// Round 1
// baseline (1149.607 us; speedup 1.0000x reference)
//
#include <hip/hip_runtime.h>

// Problem constants
#define B_ 256
#define T_ 64
#define V_ 10000
#define E_ 512
#define H_ 1024
#define G_ 4096   // 4*H

typedef __attribute__((ext_vector_type(8))) short short8;
typedef __attribute__((ext_vector_type(4))) float f32x4;

static __device__ __forceinline__ float bf2f(unsigned short u) {
    return __uint_as_float(((unsigned int)u) << 16);
}
static __device__ __forceinline__ unsigned short f2bf(float f) {
    unsigned int i = __float_as_uint(f);
    unsigned int r = (i + 0x7FFFu + ((i >> 16) & 1u)) >> 16;
    return (unsigned short)r;
}
static __device__ __forceinline__ float sigmoid_f(float x) {
    return 1.0f / (1.0f + __expf(-x));
}
static __device__ __forceinline__ float tanh_f(float x) {
    return 1.0f - 2.0f / (__expf(2.0f * x) + 1.0f);
}

// ---------------------------------------------------------------------------
// fp32 -> bf16 convert (vectorized, n4 = n/4 groups)
__global__ __launch_bounds__(256) void k_cvt(const float* __restrict__ in,
                                             unsigned short* __restrict__ out, int n4) {
    int i = blockIdx.x * 256 + threadIdx.x;
    if (i >= n4) return;
    float4 v = reinterpret_cast<const float4*>(in)[i];
    uint2 p;
    p.x = (unsigned int)f2bf(v.x) | ((unsigned int)f2bf(v.y) << 16);
    p.y = (unsigned int)f2bf(v.z) | ((unsigned int)f2bf(v.w) << 16);
    reinterpret_cast<uint2*>(out)[i] = p;
}

// ---------------------------------------------------------------------------
// W[K][N] fp32 -> WT[N][K] bf16 (tiled transpose via LDS)
__global__ __launch_bounds__(256) void k_transpose(const float* __restrict__ w,
                                                   unsigned short* __restrict__ wT,
                                                   int K, int N) {
    __shared__ float tile[32][33];
    int nblk = N >> 5;
    int bx = blockIdx.x % nblk;
    int by = blockIdx.x / nblk;
    int lx = threadIdx.x & 31;
    int ly = threadIdx.x >> 5;  // 0..7
    int k0 = by * 32, n0 = bx * 32;
#pragma unroll
    for (int i = 0; i < 32; i += 8)
        tile[ly + i][lx] = w[(size_t)(k0 + ly + i) * N + n0 + lx];
    __syncthreads();
#pragma unroll
    for (int i = 0; i < 32; i += 8)
        wT[(size_t)(n0 + ly + i) * K + k0 + lx] = f2bf(tile[lx][ly + i]);
}

// ---------------------------------------------------------------------------
// xg[B*T][G] = bf16( embed[seq] @ x2h_w + x2h_b )
// WG = 64 rows x 64 cols, 4 waves (wave = 16 rows x 64 cols), BK=32
__global__ __launch_bounds__(256) void k_xg(const int* __restrict__ seq,
                                            const unsigned short* __restrict__ emb,  // [V][E]
                                            const unsigned short* __restrict__ wT,   // [G][E]
                                            const float* __restrict__ bias,          // [G]
                                            unsigned short* __restrict__ xg) {       // [B*T][G]
    const int mb = blockIdx.x & 255;  // 256 row blocks
    const int nb = blockIdx.x >> 8;   // 64 col blocks
    const int tid = threadIdx.x;
    const int w = tid >> 6;
    const int l = tid & 63;
    const int g = l >> 4, li = l & 15;

    __shared__ int seqv[64];
    __shared__ unsigned short As[64][40];
    __shared__ unsigned short Bs[64][40];

    if (tid < 64) seqv[tid] = seq[mb * 64 + tid];
    __syncthreads();

    const int srow = tid >> 2;          // 0..63
    const int scol = (tid & 3) * 8;     // 0,8,16,24
    const unsigned short* aptr = emb + (size_t)seqv[srow] * E_ + scol;
    const unsigned short* bptr = wT + (size_t)(nb * 64 + srow) * E_ + scol;

    f32x4 acc[4] = {};
    int4 ra = *(const int4*)aptr;
    int4 rb = *(const int4*)bptr;
    for (int kk = 0; kk < E_; kk += 32) {
        *(int4*)&As[srow][scol] = ra;
        *(int4*)&Bs[srow][scol] = rb;
        __syncthreads();
        if (kk + 32 < E_) {
            ra = *(const int4*)(aptr + kk + 32);
            rb = *(const int4*)(bptr + kk + 32);
        }
        short8 af = *(const short8*)&As[w * 16 + li][g * 8];
#pragma unroll
        for (int q = 0; q < 4; ++q) {
            short8 bf = *(const short8*)&Bs[q * 16 + li][g * 8];
            acc[q] = __builtin_amdgcn_mfma_f32_16x16x32_bf16(af, bf, acc[q], 0, 0, 0);
        }
        __syncthreads();
    }
    const int m0 = mb * 64 + w * 16 + g * 4;
#pragma unroll
    for (int q = 0; q < 4; ++q) {
        int col = nb * 64 + q * 16 + li;
        float bv = bias[col];
#pragma unroll
        for (int r = 0; r < 4; ++r)
            xg[(size_t)(m0 + r) * G_ + col] = f2bf(acc[q][r] + bv);
    }
}

// ---------------------------------------------------------------------------
// One LSTM step: gates = xg_t + h @ h2h_w + h2h_b; pointwise; masked update.
// grid = 256 WGs: rb (4 blocks of 64 batch rows) x cb (64 blocks of 16 h-cols).
// Each WG computes gate cols {q*1024 + cb*16 + j : q=0..3, j=0..15}; lane holds
// i,f,g,o for its (row, h-col) entirely in registers (acc[q][r]).
__global__ __launch_bounds__(256) void k_step(const unsigned short* __restrict__ xg,   // [B][T][G]
                                              const unsigned short* __restrict__ wT,   // [G][H]
                                              const float* __restrict__ bias,          // [G]
                                              const int* __restrict__ seq_len,         // [B]
                                              unsigned short* __restrict__ h,          // [B][H] bf16
                                              float* __restrict__ c,                   // [B][H]
                                              float* __restrict__ hs,                  // [B][T][H]
                                              float* __restrict__ cs,                  // [B][T][H]
                                              int t) {
    const int rb = blockIdx.x & 3;
    const int cb = blockIdx.x >> 2;  // 0..63
    const int tid = threadIdx.x;
    const int w = tid >> 6;
    const int l = tid & 63;
    const int g = l >> 4, li = l & 15;

    __shared__ unsigned short As[64][40];
    __shared__ unsigned short Bs[64][40];

    const int srow = tid >> 2;
    const int scol = (tid & 3) * 8;
    const unsigned short* aptr = h + (size_t)(rb * 64 + srow) * H_ + scol;
    const int q_s = srow >> 4, jj_s = srow & 15;
    const unsigned short* bptr = wT + (size_t)(q_s * 1024 + cb * 16 + jj_s) * H_ + scol;

    f32x4 acc[4] = {};
    int4 ra = *(const int4*)aptr;
    int4 rb2 = *(const int4*)bptr;
    for (int kk = 0; kk < H_; kk += 32) {
        *(int4*)&As[srow][scol] = ra;
        *(int4*)&Bs[srow][scol] = rb2;
        __syncthreads();
        if (kk + 32 < H_) {
            ra = *(const int4*)(aptr + kk + 32);
            rb2 = *(const int4*)(bptr + kk + 32);
        }
        short8 af = *(const short8*)&As[w * 16 + li][g * 8];
#pragma unroll
        for (int q = 0; q < 4; ++q) {
            short8 bf = *(const short8*)&Bs[q * 16 + li][g * 8];
            acc[q] = __builtin_amdgcn_mfma_f32_16x16x32_bf16(af, bf, acc[q], 0, 0, 0);
        }
        __syncthreads();
    }

    const int hc = cb * 16 + li;
    float bv[4];
#pragma unroll
    for (int q = 0; q < 4; ++q) bv[q] = bias[q * 1024 + hc];

    const int m0 = rb * 64 + w * 16 + g * 4;
#pragma unroll
    for (int r = 0; r < 4; ++r) {
        const int m = m0 + r;
        const size_t xoff = ((size_t)m * T_ + t) * G_;
        float xi = bf2f(xg[xoff + hc]);
        float xf = bf2f(xg[xoff + 1024 + hc]);
        float xgv = bf2f(xg[xoff + 2048 + hc]);
        float xo = bf2f(xg[xoff + 3072 + hc]);
        float ig = sigmoid_f(acc[0][r] + bv[0] + xi);
        float fg = sigmoid_f(acc[1][r] + bv[1] + xf);
        float gg = tanh_f(acc[2][r] + bv[2] + xgv);
        float og = sigmoid_f(acc[3][r] + bv[3] + xo);
        const size_t hoff = (size_t)m * H_ + hc;
        float cold = c[hoff];
        float cn = fg * cold + ig * gg;
        float hn = og * tanh_f(cn);
        bool valid = t < seq_len[m];
        if (valid) {
            c[hoff] = cn;
            h[hoff] = f2bf(hn);
        }
        const size_t ooff = ((size_t)m * T_ + t) * H_ + hc;
        hs[ooff] = valid ? hn : 0.0f;
        cs[ooff] = valid ? cn : 0.0f;
    }
}

// ---------------------------------------------------------------------------
// final_hidden[B][H] = tanh(h_last @ aff_w + aff_b)
__global__ __launch_bounds__(256) void k_final(const unsigned short* __restrict__ h,   // [B][H]
                                               const unsigned short* __restrict__ wT,  // [H][H]
                                               const float* __restrict__ bias,         // [H]
                                               float* __restrict__ fin) {              // [B][H]
    const int rb = blockIdx.x & 3;
    const int nb = blockIdx.x >> 2;  // 0..15
    const int tid = threadIdx.x;
    const int w = tid >> 6;
    const int l = tid & 63;
    const int g = l >> 4, li = l & 15;

    __shared__ unsigned short As[64][40];
    __shared__ unsigned short Bs[64][40];

    const int srow = tid >> 2;
    const int scol = (tid & 3) * 8;
    const unsigned short* aptr = h + (size_t)(rb * 64 + srow) * H_ + scol;
    const unsigned short* bptr = wT + (size_t)(nb * 64 + srow) * H_ + scol;

    f32x4 acc[4] = {};
    int4 ra = *(const int4*)aptr;
    int4 rb2 = *(const int4*)bptr;
    for (int kk = 0; kk < H_; kk += 32) {
        *(int4*)&As[srow][scol] = ra;
        *(int4*)&Bs[srow][scol] = rb2;
        __syncthreads();
        if (kk + 32 < H_) {
            ra = *(const int4*)(aptr + kk + 32);
            rb2 = *(const int4*)(bptr + kk + 32);
        }
        short8 af = *(const short8*)&As[w * 16 + li][g * 8];
#pragma unroll
        for (int q = 0; q < 4; ++q) {
            short8 bf = *(const short8*)&Bs[q * 16 + li][g * 8];
            acc[q] = __builtin_amdgcn_mfma_f32_16x16x32_bf16(af, bf, acc[q], 0, 0, 0);
        }
        __syncthreads();
    }
    const int m0 = rb * 64 + w * 16 + g * 4;
#pragma unroll
    for (int q = 0; q < 4; ++q) {
        int col = nb * 64 + q * 16 + li;
        float bv = bias[col];
#pragma unroll
        for (int r = 0; r < 4; ++r)
            fin[(size_t)(m0 + r) * H_ + col] = tanh_f(acc[q][r] + bv);
    }
}

// ---------------------------------------------------------------------------
__global__ __launch_bounds__(256) void k_mask(const int* __restrict__ seq_len,
                                              float* __restrict__ mask) {
    int i = blockIdx.x * 256 + threadIdx.x;  // B*T total
    int b = i >> 6, t = i & 63;
    mask[i] = (t < seq_len[b]) ? 1.0f : 0.0f;
}

// ---------------------------------------------------------------------------
extern "C" void kernel_launch(void* const* d_in, const int* in_sizes, int n_in,
                              void* d_out, int out_size, void* d_ws, size_t ws_size,
                              hipStream_t stream) {
    const int* seq = (const int*)d_in[0];
    const int* seq_len = (const int*)d_in[1];
    const float* embed = (const float*)d_in[2];
    const float* x2h_w = (const float*)d_in[3];
    const float* x2h_b = (const float*)d_in[4];
    const float* h2h_w = (const float*)d_in[5];
    const float* h2h_b = (const float*)d_in[6];
    const float* aff_w = (const float*)d_in[7];
    const float* aff_b = (const float*)d_in[8];

    float* out = (float*)d_out;
    float* hs = out;
    float* cs = out + (size_t)B_ * T_ * H_;
    float* fin = cs + (size_t)B_ * T_ * H_;
    float* mask = fin + (size_t)B_ * H_;

    // Workspace layout (all offsets 256B-aligned); total ~161 MB.
    char* p = (char*)d_ws;
    unsigned short* emb_b = (unsigned short*)p; p += (size_t)V_ * E_ * 2;       // 10.24 MB
    unsigned short* x2h_t = (unsigned short*)p; p += (size_t)G_ * E_ * 2;       // 4 MB
    unsigned short* h2h_t = (unsigned short*)p; p += (size_t)G_ * H_ * 2;       // 8 MB
    unsigned short* aff_t = (unsigned short*)p; p += (size_t)H_ * H_ * 2;       // 2 MB
    unsigned short* xg    = (unsigned short*)p; p += (size_t)B_ * T_ * G_ * 2;  // 128 MB
    unsigned short* hbuf  = (unsigned short*)p; p += (size_t)B_ * H_ * 2;
    float* cbuf = (float*)p;

    // 1) precompute bf16 operands
    hipLaunchKernelGGL(k_cvt, dim3((V_ * E_ / 4 + 255) / 256), dim3(256), 0, stream,
                       embed, emb_b, V_ * E_ / 4);
    hipLaunchKernelGGL(k_transpose, dim3((E_ / 32) * (G_ / 32)), dim3(256), 0, stream,
                       x2h_w, x2h_t, E_, G_);
    hipLaunchKernelGGL(k_transpose, dim3((H_ / 32) * (G_ / 32)), dim3(256), 0, stream,
                       h2h_w, h2h_t, H_, G_);
    hipLaunchKernelGGL(k_transpose, dim3((H_ / 32) * (H_ / 32)), dim3(256), 0, stream,
                       aff_w, aff_t, H_, H_);

    // 2) xg = embed[seq] @ x2h_w + b
    hipLaunchKernelGGL(k_xg, dim3(256 * 64), dim3(256), 0, stream,
                       seq, emb_b, x2h_t, x2h_b, xg);

    // 3) init state
    hipMemsetAsync(hbuf, 0, (size_t)B_ * H_ * 2, stream);
    hipMemsetAsync(cbuf, 0, (size_t)B_ * H_ * 4, stream);

    // 4) recurrence
    for (int t = 0; t < T_; ++t) {
        hipLaunchKernelGGL(k_step, dim3(256), dim3(256), 0, stream,
                           xg, h2h_t, h2h_b, seq_len, hbuf, cbuf, hs, cs, t);
    }

    // 5) final affine + mask
    hipLaunchKernelGGL(k_final, dim3(64), dim3(256), 0, stream, hbuf, aff_t, aff_b, fin);
    hipLaunchKernelGGL(k_mask, dim3(B_ * T_ / 256), dim3(256), 0, stream, seq_len, mask);
}